// Round 9
// baseline (1744.397 us; speedup 1.0000x reference)
//
#include <hip/hip_runtime.h>
#include <math.h>

#ifndef M_PI
#define M_PI 3.14159265358979323846
#endif

#define BB 1024
#define SIZE 512
#define NF 128
#define WIDTH 32
#define TOTAL (SIZE*NF)

// DPP-based unsigned max reduce step (VALU latency, no LDS pipe)
#define DPP_UMAX(x, ctrl, rmask) { \
    unsigned _t = (unsigned)__builtin_amdgcn_update_dpp(0, (int)(x), (ctrl), (rmask), 0xf, false); \
    if (_t > (x)) (x) = _t; }

__device__ __forceinline__ float readlanef(float x, int l) {
    return __int_as_float(__builtin_amdgcn_readlane(__float_as_int(x), l));
}

// ---------------------------------------------------------------------------
// Single fused kernel, 1024 threads: FNO frontend + gathered build
// (A in REGISTERS: thread t owns row i = t&127, column-eighth e = t>>7,
// 16 floats = 4 float4 -> fits the 64-VGPR budget the backend insists on;
// R6-R8 with 32 floats/thread spilled 56-259 MB scratch at every hint) +
// rank-4 blocked LU with partial pivoting + logabs/sign.
// Output planar: out[b] = logabs, out[BB+b] = 0 or pi.
// ---------------------------------------------------------------------------
__global__ __launch_bounds__(1024)
void fused_kernel(
    const int*   __restrict__ n,
    const float* __restrict__ M_base,
    const float* __restrict__ lift_W,
    const float* __restrict__ lift_b,
    const float* __restrict__ spec_Wr,
    const float* __restrict__ spec_Wi,
    const float* __restrict__ pw_W,
    const float* __restrict__ pw_b,
    const float* __restrict__ proj_W,
    const float* __restrict__ proj_b,
    float* __restrict__ out)
{
    // FNO scratch
    __shared__ float nf[SIZE];
    __shared__ float c32[32], s32[32];
    __shared__ float Gre[16], Gim[16];
    __shared__ float wsum[8][32];
    __shared__ float Arr[WIDTH][16], Aii[WIDTH][16];
    __shared__ float lowr[WIDTH][16], lowi[WIDTH][16];
    __shared__ float pwl[WIDTH], cb0[WIDTH];
    __shared__ float Brr[WIDTH], Bii[WIDTH];
    // LU scratch
    __shared__ __align__(16) float pcol[128*4];   // current panel columns
    __shared__ __align__(16) float Raw[4*128];    // pivot rows (pre-panel)
    __shared__ __align__(16) float coefb[128*4];  // composite coefs per row
    __shared__ float Mb[16];
    __shared__ float pvbuf[128];
    __shared__ int   pivseq[128];
    __shared__ int   pr4[4];
    __shared__ float pooled_s[WIDTH];
    __shared__ int   Rl[NF];

    const int b = blockIdx.x;
    const int t = threadIdx.x;
    const int lane = t & 63;
    const int wave = t >> 6;

    // ================= FNO frontend (first 512 threads) =================
    if (t < 32) {
        float ang = (float)t * (2.0f * (float)M_PI / 32.0f);
        c32[t] = cosf(ang);
        s32[t] = sinf(ang);
    }
    if (t < SIZE) nf[t] = (float)n[b*SIZE + t];
    if (t < NF) Rl[t] = 0;
    __syncthreads();

    // R = first 128 nonzero indices (ballot scan, wave 0)
    if (wave == 0) {
        int base = 0;
        for (int c = 0; c < 8; ++c) {
            int p = c*64 + lane;
            bool occ = (nf[p] != 0.0f);
            unsigned long long mask = __ballot(occ);
            int prefix = __popcll(mask & ((1ull << lane) - 1ull));
            if (occ) {
                int idx = base + prefix;
                if (idx < NF) Rl[idx] = p;
            }
            base += __popcll(mask);
        }
    }

    // G[kx,ky] DFT: one point per thread (t < 512)
    if (t < SIZE) {
        float v = nf[t];
        int x = t >> 4, y = t & 15;
        float gre[16], gim[16];
        #pragma unroll
        for (int kx = 0; kx < 4; ++kx)
            #pragma unroll
            for (int ky = 0; ky < 4; ++ky) {
                int idx = (kx*x + 2*ky*y) & 31;
                gre[kx*4+ky] = v * c32[idx];
                gim[kx*4+ky] = -v * s32[idx];
            }
        #pragma unroll
        for (int m = 0; m < 16; ++m) {
            for (int off = 32; off > 0; off >>= 1) {
                gre[m] += __shfl_xor(gre[m], off, 64);
                gim[m] += __shfl_xor(gim[m], off, 64);
            }
        }
        if (lane == 0) {
            #pragma unroll
            for (int m = 0; m < 16; ++m) { wsum[wave][m] = gre[m]; wsum[wave][16+m] = gim[m]; }
        }
        // A_oc[o,m]: one (o,m) per thread
        int o = t >> 4, m = t & 15;
        float ar = 0.f, ai = 0.f;
        for (int ii = 0; ii < WIDTH; ++ii) {
            float lw = lift_W[ii];
            ar += lw * spec_Wr[ii*512 + o*16 + m];
            ai += lw * spec_Wi[ii*512 + o*16 + m];
        }
        Arr[o][m] = ar; Aii[o][m] = ai;
    }
    __syncthreads();
    if (t < 32) {
        float s = 0.f;
        #pragma unroll
        for (int w = 0; w < 8; ++w) s += wsum[w][t];
        if (t < 16) Gre[t] = s; else Gim[t-16] = s;
        // DC bias + pointwise constants
        float br = 0.f, bi = 0.f, pl = 0.f, cb = 0.f;
        for (int ii = 0; ii < WIDTH; ++ii) {
            float lb = lift_b[ii];
            br += lb * spec_Wr[ii*512 + t*16 + 0];
            bi += lb * spec_Wi[ii*512 + t*16 + 0];
            pl += lift_W[ii] * pw_W[ii*WIDTH + t];
            cb += lb * pw_W[ii*WIDTH + t];
        }
        Brr[t] = br; Bii[t] = bi;
        pwl[t] = pl;
        cb0[t] = cb + pw_b[t];
    }
    __syncthreads();
    if (t < SIZE) {
        int o = t >> 4, m = t & 15;
        float gr = Gre[m], gi = Gim[m];
        float ar = Arr[o][m], ai = Aii[o][m];
        float lr = gr*ar - gi*ai;
        float li = gr*ai + gi*ar;
        if (m == 0) { lr += 512.f * Brr[o]; li += 512.f * Bii[o]; }
        lowr[o][m] = lr; lowi[o][m] = li;
    }
    __syncthreads();
    if (t < 256) {
        const int o  = t >> 3;
        const int xg = t & 7;
        const float plo = pwl[o], cbo = cb0[o];
        float acc = 0.f;
        const float inv32 = 1.0f/32.0f, inv16 = 1.0f/16.0f;
        for (int xi = 0; xi < 4; ++xi) {
            int x = xg*4 + xi;
            float Tre[4], Tim[4];
            #pragma unroll
            for (int ky = 0; ky < 4; ++ky) { Tre[ky] = 0.f; Tim[ky] = 0.f; }
            #pragma unroll
            for (int kx = 0; kx < 4; ++kx) {
                int idx = (kx*x) & 31;
                float c = c32[idx], s = s32[idx];
                #pragma unroll
                for (int ky = 0; ky < 4; ++ky) {
                    float lr = lowr[o][kx*4+ky], li = lowi[o][kx*4+ky];
                    Tre[ky] += lr*c - li*s;
                    Tim[ky] += lr*s + li*c;
                }
            }
            #pragma unroll
            for (int ky = 0; ky < 4; ++ky) { Tre[ky] *= inv32; Tim[ky] *= inv32; }
            for (int y = 0; y < 16; ++y) {
                float hsv = Tre[0];
                #pragma unroll
                for (int ky = 1; ky < 4; ++ky) {
                    int idx = (2*ky*y) & 31;
                    hsv += 2.f*(Tre[ky]*c32[idx] - Tim[ky]*s32[idx]);
                }
                hsv *= inv16;
                float z = hsv + nf[x*16 + y]*plo + cbo;
                acc += tanhf(z);
            }
        }
        acc += __shfl_down(acc, 4, 8);
        acc += __shfl_down(acc, 2, 8);
        acc += __shfl_down(acc, 1, 8);
        if ((t & 7) == 0) pooled_s[o] = acc * (1.0f/512.0f);
    }
    __syncthreads();

    // ================= build A into registers =================
    // thread t: row i = t&127, eighth e = t>>7; owns cols e*16 .. e*16+15
    // as 4 float4 (group g holds global column-group G = e*4+g).
    const int i = t & 127;
    const int e = t >> 7;
    float4 Areg[4];
    {
        const int r = Rl[i];
        const size_t off0 = (size_t)r*NF + e*16;
        const float4* mb = (const float4*)(M_base + off0);
        const float4* pb = (const float4*)(proj_b + off0);
        #pragma unroll
        for (int g = 0; g < 4; ++g) {
            float4 a = mb[g], c = pb[g];
            Areg[g] = make_float4(a.x+c.x, a.y+c.y, a.z+c.z, a.w+c.w);
        }
        for (int o = 0; o < WIDTH; ++o) {
            const float p = pooled_s[o];
            const float4* w = (const float4*)(proj_W + (size_t)o*TOTAL + off0);
            #pragma unroll
            for (int g = 0; g < 4; ++g) {
                float4 wv = w[g];
                Areg[g].x += p*wv.x; Areg[g].y += p*wv.y;
                Areg[g].z += p*wv.z; Areg[g].w += p*wv.w;
            }
        }
    }

    // publish panel-0 column (owner: e == 0, group 0)
    if (e == 0) *((float4*)&pcol[i*4]) = Areg[0];
    __syncthreads();

    // ================= rank-4 blocked LU (3 barriers/panel) =================
    bool done_i = false;
    bool done0 = false, done1 = false;

    for (int p = 0; p < 32; ++p) {
        // pivot phase (wave 0) -- pcol already holds panel p's columns
        if (t < 64) {
            float4 r0 = *((const float4*)&pcol[lane*4]);
            float4 r1 = *((const float4*)&pcol[lane*4 + 256]);
            float v0[4] = { r0.x, r0.y, r0.z, r0.w };
            float v1[4] = { r1.x, r1.y, r1.z, r1.w };
            float lr0[4], lr1[4];
            int   prreg[4];

            #pragma unroll
            for (int k = 0; k < 4; ++k) {
                unsigned k0 = done0 ? 0u : (__float_as_uint(v0[k]) & 0x7fffffffu);
                unsigned k1 = done1 ? 0u : (__float_as_uint(v1[k]) & 0x7fffffffu);
                unsigned key = (k0 > k1) ? k0 : k1;
                DPP_UMAX(key, 0x111, 0xf);   // row_shr:1
                DPP_UMAX(key, 0x112, 0xf);   // row_shr:2
                DPP_UMAX(key, 0x114, 0xf);   // row_shr:4
                DPP_UMAX(key, 0x118, 0xf);   // row_shr:8
                DPP_UMAX(key, 0x142, 0xa);   // row_bcast:15
                DPP_UMAX(key, 0x143, 0xc);   // row_bcast:31
                const unsigned best = (unsigned)__builtin_amdgcn_readlane((int)key, 63);
                const unsigned long long b0m = __ballot(k0 == best);
                const unsigned long long b1m = __ballot(k1 == best);
                int lw, row; float pv;
                if (b0m) {
                    lw = __ffsll(b0m) - 1; row = lw;
                    pv = readlanef(v0[k], lw);
                } else {
                    lw = __ffsll(b1m) - 1; row = lw + 64;
                    pv = readlanef(v1[k], lw);
                }
                prreg[k] = row;
                const float inv = 1.0f / pv;
                float l0 = (done0 || row == lane)      ? 0.f : v0[k] * inv;
                float l1 = (done1 || row == lane + 64) ? 0.f : v1[k] * inv;
                lr0[k] = l0; lr1[k] = l1;
                if (row == lane)      done0 = true;
                if (row == lane + 64) done1 = true;
                const bool lowhalf = (row < 64);
                #pragma unroll
                for (int j = 0; j < 4; ++j) if (j > k) {
                    float ukj = lowhalf ? readlanef(v0[j], lw) : readlanef(v1[j], lw);
                    v0[j] -= l0 * ukj;
                    v1[j] -= l1 * ukj;
                }
                if (lane == 0) { pivseq[4*p+k] = row; pvbuf[4*p+k] = pv; }
            }

            // L11 strict-lower entries via readlane (uniform)
            const int pa = prreg[1], pb_ = prreg[2], pc = prreg[3];
            const float Lt10 = (pa  < 64) ? readlanef(lr0[0], pa)  : readlanef(lr1[0], pa - 64);
            const float Lt20 = (pb_ < 64) ? readlanef(lr0[0], pb_) : readlanef(lr1[0], pb_ - 64);
            const float Lt21 = (pb_ < 64) ? readlanef(lr0[1], pb_) : readlanef(lr1[1], pb_ - 64);
            const float Lt30 = (pc  < 64) ? readlanef(lr0[0], pc)  : readlanef(lr1[0], pc - 64);
            const float Lt31 = (pc  < 64) ? readlanef(lr0[1], pc)  : readlanef(lr1[1], pc - 64);
            const float Lt32 = (pc  < 64) ? readlanef(lr0[2], pc)  : readlanef(lr1[2], pc - 64);

            // M = (I+Lt)^{-1} closed form (unit lower)
            const float m10 = -Lt10;
            const float m21 = -Lt21;
            const float m32 = -Lt32;
            const float m20 = -Lt20 + Lt21*Lt10;
            const float m31 = -Lt31 + Lt32*Lt21;
            const float m30 = -Lt30 + Lt31*Lt10 + Lt32*Lt20 - Lt32*Lt21*Lt10;

            if (lane == 0) {
                pr4[0] = prreg[0]; pr4[1] = prreg[1];
                pr4[2] = prreg[2]; pr4[3] = prreg[3];
                Mb[0]=1.f;  Mb[1]=0.f;  Mb[2]=0.f;  Mb[3]=0.f;
                Mb[4]=m10;  Mb[5]=1.f;  Mb[6]=0.f;  Mb[7]=0.f;
                Mb[8]=m20;  Mb[9]=m21;  Mb[10]=1.f; Mb[11]=0.f;
                Mb[12]=m30; Mb[13]=m31; Mb[14]=m32; Mb[15]=1.f;
            }

            // composite coefs: coef = -(lrow . M)
            {
                float c0 = -(lr0[0] + lr0[1]*m10 + lr0[2]*m20 + lr0[3]*m30);
                float c1 = -(lr0[1] + lr0[2]*m21 + lr0[3]*m31);
                float c2 = -(lr0[2] + lr0[3]*m32);
                float c3 = -(lr0[3]);
                *((float4*)&coefb[lane*4]) = make_float4(c0, c1, c2, c3);
                float d0 = -(lr1[0] + lr1[1]*m10 + lr1[2]*m20 + lr1[3]*m30);
                float d1 = -(lr1[1] + lr1[2]*m21 + lr1[3]*m31);
                float d2 = -(lr1[2] + lr1[3]*m32);
                float d3 = -(lr1[3]);
                *((float4*)&coefb[(lane+64)*4]) = make_float4(d0, d1, d2, d3);
            }
        }
        __syncthreads();   // barrier A: pr4/Mb/coefb ready

        // pivot-row owners publish their register groups (pre-update values)
        int fp = -1;
        #pragma unroll
        for (int s = 0; s < 4; ++s) if (i == pr4[s]) fp = s;
        if (fp >= 0) {
            #pragma unroll
            for (int g = 0; g < 4; ++g)
                *((float4*)&Raw[fp*128 + e*16 + g*4]) = Areg[g];
        }
        __syncthreads();   // barrier B: Raw ready

        // rank-4 update in registers; fuse next-panel pcol publication
        if (fp >= 0) {
            const float m0 = Mb[fp*4+0], m1 = Mb[fp*4+1], m2 = Mb[fp*4+2], m3 = Mb[fp*4+3];
            #pragma unroll
            for (int g = 0; g < 4; ++g) {
                if (e*4 + g > p) {
                    const int cbase = e*16 + g*4;
                    float4 r0v = *((const float4*)&Raw[0*128 + cbase]);
                    float4 r1v = *((const float4*)&Raw[1*128 + cbase]);
                    float4 r2v = *((const float4*)&Raw[2*128 + cbase]);
                    float4 r3v = *((const float4*)&Raw[3*128 + cbase]);
                    Areg[g].x = m0*r0v.x + m1*r1v.x + m2*r2v.x + m3*r3v.x;
                    Areg[g].y = m0*r0v.y + m1*r1v.y + m2*r2v.y + m3*r3v.y;
                    Areg[g].z = m0*r0v.z + m1*r1v.z + m2*r2v.z + m3*r3v.z;
                    Areg[g].w = m0*r0v.w + m1*r1v.w + m2*r2v.w + m3*r3v.w;
                }
            }
            done_i = true;
        } else if (!done_i) {
            const float4 cf = *((const float4*)&coefb[i*4]);
            #pragma unroll
            for (int g = 0; g < 4; ++g) {
                if (e*4 + g > p) {
                    const int cbase = e*16 + g*4;
                    float4 r0v = *((const float4*)&Raw[0*128 + cbase]);
                    float4 r1v = *((const float4*)&Raw[1*128 + cbase]);
                    float4 r2v = *((const float4*)&Raw[2*128 + cbase]);
                    float4 r3v = *((const float4*)&Raw[3*128 + cbase]);
                    Areg[g].x += cf.x*r0v.x + cf.y*r1v.x + cf.z*r2v.x + cf.w*r3v.x;
                    Areg[g].y += cf.x*r0v.y + cf.y*r1v.y + cf.z*r2v.y + cf.w*r3v.y;
                    Areg[g].z += cf.x*r0v.z + cf.y*r1v.z + cf.z*r2v.z + cf.w*r3v.z;
                    Areg[g].w += cf.x*r0v.w + cf.y*r1v.w + cf.z*r2v.w + cf.w*r3v.w;
                }
            }
        }
        // publish next panel's column group (value just updated in registers)
        if (p < 31) {
            const int np = p + 1;
            if (e == (np >> 2)) {
                const int ng = np & 3;
                float4 v = Areg[0];
                #pragma unroll
                for (int g = 1; g < 4; ++g) if (g == ng) v = Areg[g];
                *((float4*)&pcol[i*4]) = v;
            }
        }
        __syncthreads();   // barrier C: Areg stable + next pcol ready
    }

    // ================= logabs + sign =================
    if (t < 64) {
        float d0 = pvbuf[lane], d1 = pvbuf[lane + 64];
        int   ps0 = pivseq[lane], ps1 = pivseq[lane + 64];
        float ls = logf(fabsf(d0)) + logf(fabsf(d1));
        int neg = ((d0 < 0.f) ? 1 : 0) ^ ((d1 < 0.f) ? 1 : 0);
        #pragma unroll
        for (int off = 32; off > 0; off >>= 1) {
            ls  += __shfl_xor(ls,  off, 64);
            neg ^= __shfl_xor(neg, off, 64);
        }
        // permutation parity via cycle chase, registers + readlane (uniform)
        unsigned long long vis0 = 0ull, vis1 = 0ull;
        int trans = 0;
        for (int k = 0; k < 128; ++k) {
            bool vk = (k < 64) ? ((vis0 >> k) & 1ull) : ((vis1 >> (k - 64)) & 1ull);
            if (!vk) {
                int j = k, len = 0;
                while (true) {
                    bool vj = (j < 64) ? ((vis0 >> j) & 1ull) : ((vis1 >> (j - 64)) & 1ull);
                    if (vj) break;
                    if (j < 64) vis0 |= (1ull << j); else vis1 |= (1ull << (j - 64));
                    j = (j < 64) ? __builtin_amdgcn_readlane(ps0, j)
                                 : __builtin_amdgcn_readlane(ps1, j - 64);
                    ++len;
                }
                trans += len - 1;
            }
        }
        if (lane == 0) {
            int parity = (neg ^ (trans & 1)) & 1;
            out[b]      = ls;
            out[BB + b] = parity ? (float)M_PI : 0.0f;
        }
    }
}

// ---------------------------------------------------------------------------
extern "C" void kernel_launch(void* const* d_in, const int* in_sizes, int n_in,
                              void* d_out, int out_size, void* d_ws, size_t ws_size,
                              hipStream_t stream) {
    const int*   n       = (const int*)  d_in[0];
    const float* M_base  = (const float*)d_in[1];
    const float* lift_W  = (const float*)d_in[2];
    const float* lift_b  = (const float*)d_in[3];
    const float* spec_Wr = (const float*)d_in[4];
    const float* spec_Wi = (const float*)d_in[5];
    const float* pw_W    = (const float*)d_in[6];
    const float* pw_b    = (const float*)d_in[7];
    const float* proj_W  = (const float*)d_in[8];
    const float* proj_b  = (const float*)d_in[9];

    fused_kernel<<<BB, 1024, 0, stream>>>(n, M_base, lift_W, lift_b, spec_Wr, spec_Wi,
                                          pw_W, pw_b, proj_W, proj_b, (float*)d_out);
}

// Round 10
// 437.510 us; speedup vs baseline: 3.9871x; 3.9871x over previous
//
#include <hip/hip_runtime.h>
#include <math.h>

#ifndef M_PI
#define M_PI 3.14159265358979323846
#endif

#define BB 1024
#define SIZE 512
#define NF 128
#define WIDTH 32
#define TOTAL (SIZE*NF)

// DPP-based unsigned max reduce step (VALU latency, no LDS pipe)
#define DPP_UMAX(x, ctrl, rmask) { \
    unsigned _t = (unsigned)__builtin_amdgcn_update_dpp(0, (int)(x), (ctrl), (rmask), 0xf, false); \
    if (_t > (x)) (x) = _t; }

__device__ __forceinline__ float readlanef(float x, int l) {
    return __int_as_float(__builtin_amdgcn_readlane(__float_as_int(x), l));
}

// ---------------------------------------------------------------------------
// Kernel 1: per-sample FNO frontend -> pooled[b][32], pos[r][b] (gather map)
// pos[r][b] = index of row r within sample b's gathered matrix, or -1.
// ---------------------------------------------------------------------------
__global__ __launch_bounds__(256) void fno_pooled_kernel(
    const int*   __restrict__ n,
    const float* __restrict__ lift_W,
    const float* __restrict__ lift_b,
    const float* __restrict__ spec_Wr,
    const float* __restrict__ spec_Wi,
    const float* __restrict__ pw_W,
    const float* __restrict__ pw_b,
    float* __restrict__ pooled_g,
    signed char* __restrict__ pos_g)
{
    __shared__ float nf[SIZE];
    __shared__ float c32[32], s32[32];
    __shared__ float Gre[16], Gim[16];
    __shared__ float wsum[4][32];
    __shared__ float Arr[WIDTH][16], Aii[WIDTH][16];
    __shared__ float lowr[WIDTH][16], lowi[WIDTH][16];
    __shared__ float pwl[WIDTH], cb0[WIDTH];
    __shared__ float Brr[WIDTH], Bii[WIDTH];

    const int b = blockIdx.x;
    const int t = threadIdx.x;
    const int lane = t & 63;
    const int wave = t >> 6;

    if (t < 32) {
        float ang = (float)t * (2.0f * (float)M_PI / 32.0f);
        c32[t] = cosf(ang);
        s32[t] = sinf(ang);
    }
    for (int p = t; p < SIZE; p += 256) nf[p] = (float)n[b*SIZE + p];
    __syncthreads();

    // gather map via ballot scan (wave 0): pos[r][b]
    if (wave == 0) {
        int base = 0;
        for (int c = 0; c < 8; ++c) {
            int p = c*64 + lane;
            bool occ = (nf[p] != 0.0f);
            unsigned long long mask = __ballot(occ);
            int prefix = __popcll(mask & ((1ull << lane) - 1ull));
            int pos = base + prefix;
            pos_g[(size_t)p*BB + b] = (occ && pos < NF) ? (signed char)pos : (signed char)-1;
            base += __popcll(mask);
        }
    }

    float gre[16], gim[16];
    #pragma unroll
    for (int m = 0; m < 16; ++m) { gre[m] = 0.f; gim[m] = 0.f; }
    for (int p = t; p < SIZE; p += 256) {
        float v = nf[p];
        int x = p >> 4, y = p & 15;
        #pragma unroll
        for (int kx = 0; kx < 4; ++kx) {
            #pragma unroll
            for (int ky = 0; ky < 4; ++ky) {
                int idx = (kx*x + 2*ky*y) & 31;
                gre[kx*4+ky] += v * c32[idx];
                gim[kx*4+ky] -= v * s32[idx];
            }
        }
    }
    #pragma unroll
    for (int m = 0; m < 16; ++m) {
        for (int off = 32; off > 0; off >>= 1) {
            gre[m] += __shfl_xor(gre[m], off, 64);
            gim[m] += __shfl_xor(gim[m], off, 64);
        }
    }
    if (lane == 0) {
        #pragma unroll
        for (int m = 0; m < 16; ++m) { wsum[wave][m] = gre[m]; wsum[wave][16+m] = gim[m]; }
    }
    __syncthreads();
    if (t < 32) {
        float s = wsum[0][t] + wsum[1][t] + wsum[2][t] + wsum[3][t];
        if (t < 16) Gre[t] = s; else Gim[t-16] = s;
    }

    for (int idx = t; idx < 512; idx += 256) {
        int o = idx >> 4, m = idx & 15;
        float ar = 0.f, ai = 0.f;
        for (int ii = 0; ii < WIDTH; ++ii) {
            float lw = lift_W[ii];
            ar += lw * spec_Wr[ii*512 + o*16 + m];
            ai += lw * spec_Wi[ii*512 + o*16 + m];
        }
        Arr[o][m] = ar; Aii[o][m] = ai;
    }
    if (t < 32) {
        float br = 0.f, bi = 0.f, pl = 0.f, cb = 0.f;
        for (int ii = 0; ii < WIDTH; ++ii) {
            float lb = lift_b[ii];
            br += lb * spec_Wr[ii*512 + t*16 + 0];
            bi += lb * spec_Wi[ii*512 + t*16 + 0];
            pl += lift_W[ii] * pw_W[ii*WIDTH + t];
            cb += lb * pw_W[ii*WIDTH + t];
        }
        Brr[t] = br; Bii[t] = bi;
        pwl[t] = pl;
        cb0[t] = cb + pw_b[t];
    }
    __syncthreads();

    for (int idx = t; idx < 512; idx += 256) {
        int o = idx >> 4, m = idx & 15;
        float gr = Gre[m], gi = Gim[m];
        float ar = Arr[o][m], ai = Aii[o][m];
        float lr = gr*ar - gi*ai;
        float li = gr*ai + gi*ar;
        if (m == 0) { lr += 512.f * Brr[o]; li += 512.f * Bii[o]; }
        lowr[o][m] = lr; lowi[o][m] = li;
    }
    __syncthreads();

    const int o  = t >> 3;
    const int xg = t & 7;
    const float plo = pwl[o], cbo = cb0[o];
    float acc = 0.f;
    const float inv32 = 1.0f/32.0f, inv16 = 1.0f/16.0f;
    for (int xi = 0; xi < 4; ++xi) {
        int x = xg*4 + xi;
        float Tre[4], Tim[4];
        #pragma unroll
        for (int ky = 0; ky < 4; ++ky) { Tre[ky] = 0.f; Tim[ky] = 0.f; }
        #pragma unroll
        for (int kx = 0; kx < 4; ++kx) {
            int idx = (kx*x) & 31;
            float c = c32[idx], s = s32[idx];
            #pragma unroll
            for (int ky = 0; ky < 4; ++ky) {
                float lr = lowr[o][kx*4+ky], li = lowi[o][kx*4+ky];
                Tre[ky] += lr*c - li*s;
                Tim[ky] += lr*s + li*c;
            }
        }
        #pragma unroll
        for (int ky = 0; ky < 4; ++ky) { Tre[ky] *= inv32; Tim[ky] *= inv32; }
        for (int y = 0; y < 16; ++y) {
            float hsv = Tre[0];
            #pragma unroll
            for (int ky = 1; ky < 4; ++ky) {
                int idx = (2*ky*y) & 31;
                hsv += 2.f*(Tre[ky]*c32[idx] - Tim[ky]*s32[idx]);
            }
            hsv *= inv16;
            float z = hsv + nf[x*16 + y]*plo + cbo;
            acc += tanhf(z);
        }
    }
    acc += __shfl_down(acc, 4, 8);
    acc += __shfl_down(acc, 2, 8);
    acc += __shfl_down(acc, 1, 8);
    if ((t & 7) == 0) pooled_g[b*WIDTH + o] = acc * (1.0f/512.0f);
}

// ---------------------------------------------------------------------------
// Kernel 2: r-major gathered build. Block = (row r, tile of 256 samples).
// proj_W segment for r lives in registers (32 floats/thread) and is reused
// across 256 samples -> proj_W traffic 2 GB -> 128 MB. Writes A_ws coalesced.
// ---------------------------------------------------------------------------
__global__ __launch_bounds__(128) void build_kernel(
    const float* __restrict__ M_base,
    const float* __restrict__ proj_W,
    const float* __restrict__ proj_b,
    const float* __restrict__ pooled_g,
    const signed char* __restrict__ pos_g,
    float* __restrict__ A_ws)
{
    __shared__ float pooled_l[256*WIDTH];   // 32 KB
    __shared__ signed char posl[256];

    const int r  = blockIdx.x >> 2;
    const int b0 = (blockIdx.x & 3) * 256;
    const int j  = threadIdx.x;

    // stage pooled tile + pos tile
    {
        const float4* src = (const float4*)(pooled_g + (size_t)b0*WIDTH);
        float4* dst = (float4*)pooled_l;
        for (int idx = j; idx < 256*WIDTH/4; idx += 128) dst[idx] = src[idx];
        if (j < 64) ((int*)posl)[j] = ((const int*)(pos_g + (size_t)r*BB + b0))[j];
    }

    float wj[WIDTH];
    #pragma unroll
    for (int o = 0; o < WIDTH; ++o) wj[o] = proj_W[(size_t)o*TOTAL + r*NF + j];
    const float base = M_base[r*NF + j] + proj_b[r*NF + j];
    __syncthreads();

    for (int bb = 0; bb < 256; ++bb) {
        int pos = posl[bb];                  // uniform across block
        if (pos < 0) continue;
        const float* pl = &pooled_l[bb*WIDTH];
        float acc = base;
        #pragma unroll
        for (int o = 0; o < WIDTH; ++o) acc += pl[o]*wj[o];
        A_ws[((size_t)(b0+bb)*NF + pos)*NF + j] = acc;
    }
}

// ---------------------------------------------------------------------------
// Kernel 3: rank-4 blocked LU, A in REGISTERS, dedicated pivot wave.
// 576 threads: wave 0 = pivot/factorize only (owns no matrix data -> its
// live set never stacks with Areg); waves 1-8 (u = t-64): row i = u&127,
// quarter q = u>>7, 8 float4 of A. LDS = 7 KB exchange buffers only.
// Output planar: out[b] = logabs, out[BB+b] = 0 or pi.
// ---------------------------------------------------------------------------
__global__ __launch_bounds__(576) void lu_kernel(
    const float* __restrict__ A_ws,
    float* __restrict__ out)
{
    __shared__ __align__(16) float pcol[128*4];
    __shared__ __align__(16) float Raw[4*128];
    __shared__ __align__(16) float coefb[128*4];
    __shared__ float Mb[16];
    __shared__ float pvbuf[128];
    __shared__ int   pivseq[128];
    __shared__ int   pr4[4];

    const int b = blockIdx.x;
    const int t = threadIdx.x;
    const int lane = t & 63;
    const int u = t - 64;
    const int i = u & 127;
    const int q = (u >> 7) & 3;

    float4 Areg[8];
    if (t >= 64) {
        const float4* src = (const float4*)(A_ws + (size_t)b*(NF*NF) + i*NF + q*32);
        #pragma unroll
        for (int g = 0; g < 8; ++g) Areg[g] = src[g];
        if (q == 0) *((float4*)&pcol[i*4]) = Areg[0];
    }
    __syncthreads();

    bool done_i = false;
    bool done0 = false, done1 = false;

    for (int p = 0; p < 32; ++p) {
        // ---- pivot phase: wave 0 only, matrix waves idle at barrier ----
        if (t < 64) {
            float4 r0 = *((const float4*)&pcol[lane*4]);
            float4 r1 = *((const float4*)&pcol[lane*4 + 256]);
            float v0[4] = { r0.x, r0.y, r0.z, r0.w };
            float v1[4] = { r1.x, r1.y, r1.z, r1.w };
            float lr0[4], lr1[4];
            int   prreg[4];

            #pragma unroll
            for (int k = 0; k < 4; ++k) {
                unsigned k0 = done0 ? 0u : (__float_as_uint(v0[k]) & 0x7fffffffu);
                unsigned k1 = done1 ? 0u : (__float_as_uint(v1[k]) & 0x7fffffffu);
                unsigned key = (k0 > k1) ? k0 : k1;
                DPP_UMAX(key, 0x111, 0xf);   // row_shr:1
                DPP_UMAX(key, 0x112, 0xf);   // row_shr:2
                DPP_UMAX(key, 0x114, 0xf);   // row_shr:4
                DPP_UMAX(key, 0x118, 0xf);   // row_shr:8
                DPP_UMAX(key, 0x142, 0xa);   // row_bcast:15
                DPP_UMAX(key, 0x143, 0xc);   // row_bcast:31
                const unsigned best = (unsigned)__builtin_amdgcn_readlane((int)key, 63);
                const unsigned long long b0m = __ballot(k0 == best);
                const unsigned long long b1m = __ballot(k1 == best);
                int lw, row; float pv;
                if (b0m) {
                    lw = __ffsll(b0m) - 1; row = lw;
                    pv = readlanef(v0[k], lw);
                } else {
                    lw = __ffsll(b1m) - 1; row = lw + 64;
                    pv = readlanef(v1[k], lw);
                }
                prreg[k] = row;
                const float inv = 1.0f / pv;
                float l0 = (done0 || row == lane)      ? 0.f : v0[k] * inv;
                float l1 = (done1 || row == lane + 64) ? 0.f : v1[k] * inv;
                lr0[k] = l0; lr1[k] = l1;
                if (row == lane)      done0 = true;
                if (row == lane + 64) done1 = true;
                const bool lowhalf = (row < 64);
                #pragma unroll
                for (int j = 0; j < 4; ++j) if (j > k) {
                    float ukj = lowhalf ? readlanef(v0[j], lw) : readlanef(v1[j], lw);
                    v0[j] -= l0 * ukj;
                    v1[j] -= l1 * ukj;
                }
                if (lane == 0) { pivseq[4*p+k] = row; pvbuf[4*p+k] = pv; }
            }

            const int pa = prreg[1], pb_ = prreg[2], pc = prreg[3];
            const float Lt10 = (pa  < 64) ? readlanef(lr0[0], pa)  : readlanef(lr1[0], pa - 64);
            const float Lt20 = (pb_ < 64) ? readlanef(lr0[0], pb_) : readlanef(lr1[0], pb_ - 64);
            const float Lt21 = (pb_ < 64) ? readlanef(lr0[1], pb_) : readlanef(lr1[1], pb_ - 64);
            const float Lt30 = (pc  < 64) ? readlanef(lr0[0], pc)  : readlanef(lr1[0], pc - 64);
            const float Lt31 = (pc  < 64) ? readlanef(lr0[1], pc)  : readlanef(lr1[1], pc - 64);
            const float Lt32 = (pc  < 64) ? readlanef(lr0[2], pc)  : readlanef(lr1[2], pc - 64);

            const float m10 = -Lt10;
            const float m21 = -Lt21;
            const float m32 = -Lt32;
            const float m20 = -Lt20 + Lt21*Lt10;
            const float m31 = -Lt31 + Lt32*Lt21;
            const float m30 = -Lt30 + Lt31*Lt10 + Lt32*Lt20 - Lt32*Lt21*Lt10;

            if (lane == 0) {
                pr4[0] = prreg[0]; pr4[1] = prreg[1];
                pr4[2] = prreg[2]; pr4[3] = prreg[3];
                Mb[0]=1.f;  Mb[1]=0.f;  Mb[2]=0.f;  Mb[3]=0.f;
                Mb[4]=m10;  Mb[5]=1.f;  Mb[6]=0.f;  Mb[7]=0.f;
                Mb[8]=m20;  Mb[9]=m21;  Mb[10]=1.f; Mb[11]=0.f;
                Mb[12]=m30; Mb[13]=m31; Mb[14]=m32; Mb[15]=1.f;
            }
            {
                float c0 = -(lr0[0] + lr0[1]*m10 + lr0[2]*m20 + lr0[3]*m30);
                float c1 = -(lr0[1] + lr0[2]*m21 + lr0[3]*m31);
                float c2 = -(lr0[2] + lr0[3]*m32);
                float c3 = -(lr0[3]);
                *((float4*)&coefb[lane*4]) = make_float4(c0, c1, c2, c3);
                float d0 = -(lr1[0] + lr1[1]*m10 + lr1[2]*m20 + lr1[3]*m30);
                float d1 = -(lr1[1] + lr1[2]*m21 + lr1[3]*m31);
                float d2 = -(lr1[2] + lr1[3]*m32);
                float d3 = -(lr1[3]);
                *((float4*)&coefb[(lane+64)*4]) = make_float4(d0, d1, d2, d3);
            }
        }
        __syncthreads();   // barrier A: pr4/Mb/coefb ready

        int fp = -1;
        if (t >= 64) {
            #pragma unroll
            for (int s = 0; s < 4; ++s) if (i == pr4[s]) fp = s;
            if (fp >= 0) {
                #pragma unroll
                for (int g = 0; g < 8; ++g)
                    *((float4*)&Raw[fp*128 + q*32 + g*4]) = Areg[g];
            }
        }
        __syncthreads();   // barrier B: Raw ready

        if (t >= 64) {
            if (fp >= 0 || !done_i) {
                float cf[4];
                if (fp >= 0) {
                    #pragma unroll
                    for (int s = 0; s < 4; ++s) cf[s] = Mb[fp*4 + s];
                } else {
                    #pragma unroll
                    for (int s = 0; s < 4; ++s) cf[s] = coefb[i*4 + s];
                }
                #pragma unroll
                for (int g = 0; g < 8; ++g) {
                    if (q*8 + g > p) {
                        const int cbase = q*32 + g*4;
                        float4 own = (fp >= 0) ? make_float4(0.f,0.f,0.f,0.f) : Areg[g];
                        #pragma unroll
                        for (int s = 0; s < 4; ++s) {
                            const float c = cf[s];
                            const float4 rv = *((const float4*)&Raw[s*128 + cbase]);
                            own.x += c*rv.x; own.y += c*rv.y;
                            own.z += c*rv.z; own.w += c*rv.w;
                        }
                        Areg[g] = own;
                    }
                }
                if (fp >= 0) done_i = true;
            }
            // publish next panel's column group (value just updated)
            if (p < 31) {
                const int np = p + 1;
                if (q == (np >> 3)) {
                    const int ng = np & 7;
                    float4 v = Areg[0];
                    #pragma unroll
                    for (int g = 1; g < 8; ++g) if (g == ng) v = Areg[g];
                    *((float4*)&pcol[i*4]) = v;
                }
            }
        }
        __syncthreads();   // barrier C: Areg stable + next pcol ready
    }

    // ---- logabs + sign (wave 0) ----
    if (t < 64) {
        float d0 = pvbuf[lane], d1 = pvbuf[lane + 64];
        int   ps0 = pivseq[lane], ps1 = pivseq[lane + 64];
        float ls = logf(fabsf(d0)) + logf(fabsf(d1));
        int neg = ((d0 < 0.f) ? 1 : 0) ^ ((d1 < 0.f) ? 1 : 0);
        #pragma unroll
        for (int off = 32; off > 0; off >>= 1) {
            ls  += __shfl_xor(ls,  off, 64);
            neg ^= __shfl_xor(neg, off, 64);
        }
        unsigned long long vis0 = 0ull, vis1 = 0ull;
        int trans = 0;
        for (int k = 0; k < 128; ++k) {
            bool vk = (k < 64) ? ((vis0 >> k) & 1ull) : ((vis1 >> (k - 64)) & 1ull);
            if (!vk) {
                int j = k, len = 0;
                while (true) {
                    bool vj = (j < 64) ? ((vis0 >> j) & 1ull) : ((vis1 >> (j - 64)) & 1ull);
                    if (vj) break;
                    if (j < 64) vis0 |= (1ull << j); else vis1 |= (1ull << (j - 64));
                    j = (j < 64) ? __builtin_amdgcn_readlane(ps0, j)
                                 : __builtin_amdgcn_readlane(ps1, j - 64);
                    ++len;
                }
                trans += len - 1;
            }
        }
        if (lane == 0) {
            int parity = (neg ^ (trans & 1)) & 1;
            out[b]      = ls;
            out[BB + b] = parity ? (float)M_PI : 0.0f;
        }
    }
}

// ---------------------------------------------------------------------------
extern "C" void kernel_launch(void* const* d_in, const int* in_sizes, int n_in,
                              void* d_out, int out_size, void* d_ws, size_t ws_size,
                              hipStream_t stream) {
    const int*   n       = (const int*)  d_in[0];
    const float* M_base  = (const float*)d_in[1];
    const float* lift_W  = (const float*)d_in[2];
    const float* lift_b  = (const float*)d_in[3];
    const float* spec_Wr = (const float*)d_in[4];
    const float* spec_Wi = (const float*)d_in[5];
    const float* pw_W    = (const float*)d_in[6];
    const float* pw_b    = (const float*)d_in[7];
    const float* proj_W  = (const float*)d_in[8];
    const float* proj_b  = (const float*)d_in[9];

    // ws layout: pooled 128KB | pos 512KB | (align 1MB) A_ws 64MB
    float*       pooled = (float*)d_ws;
    signed char* pos    = (signed char*)((char*)d_ws + 128*1024);
    float*       A_ws   = (float*)((char*)d_ws + (1 << 20));

    fno_pooled_kernel<<<BB, 256, 0, stream>>>(n, lift_W, lift_b, spec_Wr, spec_Wi,
                                              pw_W, pw_b, pooled, pos);
    build_kernel<<<SIZE*4, 128, 0, stream>>>(M_base, proj_W, proj_b, pooled, pos, A_ws);
    lu_kernel<<<BB, 576, 0, stream>>>(A_ws, (float*)d_out);
}